// Round 9
// baseline (284.495 us; speedup 1.0000x reference)
//
#include <hip/hip_runtime.h>

#define NN 50000
#define NE 800000
#define NE_HALF 400000
#define F_IN 128
#define HID 256
#define N_CLS 64
#define SCAN_BLOCKS ((NN + 255) / 256)   // 196
#define HEPT 4                           // edges per thread in place
#define HB2 ((NE + 256 * HEPT - 1) / (256 * HEPT))        // 782 edge blocks (place)
#define HEPT_H 2                         // edges per thread in hist
#define HB_H ((NE_HALF + 256 * HEPT_H - 1) / (256 * HEPT_H))  // 782 blocks per hist half
#define CF_BLOCKS 36                     // compose 515x256 tiles: 9 row x 4 col
#define CL_BLOCKS 9                      // compose 515x64 tiles
#define GA_BLOCKS ((NN + 127) / 128)     // 391 gemm row-blocks
#define GG_BLOCKS ((NN + 31) / 32)       // 1563 gather blocks
#define CROWS 515                        // basis: X,AX,A2X,A3X (4*128) + 1,d,Ad

typedef _Float16 half8 __attribute__((ext_vector_type(8)));
typedef float f32x4 __attribute__((ext_vector_type(4)));

// ================= affine-map composition =================
__device__ __forceinline__ const float* virtC1_row(int r, const float* W0s,
                                                   const float* W0n, const float* b0) {
    if (r < 0) return nullptr;
    if (r < 128) return W0s + (size_t)r * 256;
    if (r < 256) return W0n + (size_t)(r - 128) * 256;
    if (r == 512) return b0;
    return nullptr;
}

__device__ __forceinline__ int shift_src(int r) {
    if (r >= 128 && r < 512) return r - 128;
    if (r == 513) return 512;
    if (r == 514) return 513;
    return -1;
}

__device__ __forceinline__ void compose_first_dev(
    int bx, const float* __restrict__ W0s, const float* __restrict__ W0n,
    const float* __restrict__ b0,
    const float* __restrict__ B1, const float* __restrict__ B2,
    const float* __restrict__ brow, float* __restrict__ C)
{
    __shared__ float As[64][17];
    __shared__ float Bs[16][64];
    const int tid = threadIdx.x;
    const int tx = tid & 15, ty = tid >> 4;
    const int row0 = (bx % 9) * 64;
    const int col0 = (bx / 9) * 64;
    const int lr = tid >> 2, lc = tid & 3;
    const int br = tid >> 4, bc = tid & 15;

    const int grow = row0 + lr;
    const int srcr0 = (grow < CROWS) ? grow : -1;
    const float* ap0 = virtC1_row(srcr0, W0s, W0n, b0);
    const float* ap1 = virtC1_row(shift_src(grow), W0s, W0n, b0);

    float acc[4][4] = {};

    float4 av = ap0 ? *(const float4*)(ap0 + lc * 4) : make_float4(0.f, 0.f, 0.f, 0.f);
    float4 bv = *(const float4*)(B1 + (size_t)br * 256 + col0 + bc * 4);

    for (int s = 0; s < 32; ++s) {
        As[lr][lc * 4 + 0] = av.x;
        As[lr][lc * 4 + 1] = av.y;
        As[lr][lc * 4 + 2] = av.z;
        As[lr][lc * 4 + 3] = av.w;
        *(float4*)&Bs[br][bc * 4] = bv;
        __syncthreads();
        if (s + 1 < 32) {
            int pass = (s + 1) >> 4;
            int k0 = ((s + 1) & 15) << 4;
            const float* ap = pass ? ap1 : ap0;
            const float* B = pass ? B2 : B1;
            av = ap ? *(const float4*)(ap + k0 + lc * 4) : make_float4(0.f, 0.f, 0.f, 0.f);
            bv = *(const float4*)(B + (size_t)(k0 + br) * 256 + col0 + bc * 4);
        }
        #pragma unroll
        for (int k = 0; k < 16; ++k) {
            float a[4];
            #pragma unroll
            for (int i = 0; i < 4; ++i) a[i] = As[ty * 4 + i][k];
            float4 bb = *(const float4*)&Bs[k][tx * 4];
            const float b[4] = {bb.x, bb.y, bb.z, bb.w};
            #pragma unroll
            for (int i = 0; i < 4; ++i)
                #pragma unroll
                for (int j = 0; j < 4; ++j)
                    acc[i][j] += a[i] * b[j];
        }
        __syncthreads();
    }

    #pragma unroll
    for (int i = 0; i < 4; ++i) {
        int r = row0 + ty * 4 + i;
        if (r < CROWS) {
            #pragma unroll
            for (int j = 0; j < 4; ++j) {
                float v = acc[i][j];
                if (r == 512) v += brow[col0 + tx * 4 + j];
                C[(size_t)r * 256 + col0 + tx * 4 + j] = v;
            }
        }
    }
}

__device__ __forceinline__ void compose_mid_dev(
    int bx, const float* __restrict__ A,
    const float* __restrict__ B1, const float* __restrict__ B2,
    const float* __restrict__ brow, float* __restrict__ C)
{
    __shared__ float As[64][17];
    __shared__ float Bs[16][64];
    const int tid = threadIdx.x;
    const int tx = tid & 15, ty = tid >> 4;
    const int row0 = (bx % 9) * 64;
    const int col0 = (bx / 9) * 64;
    const int lr = tid >> 2, lc = tid & 3;
    const int br = tid >> 4, bc = tid & 15;

    const int grow = row0 + lr;
    const int p0 = (grow < CROWS) ? grow : -1;
    const int p1 = shift_src(grow);

    float acc[4][4] = {};

    float4 av = (p0 >= 0) ? *(const float4*)(A + (size_t)p0 * 256 + lc * 4)
                          : make_float4(0.f, 0.f, 0.f, 0.f);
    float4 bv = *(const float4*)(B1 + (size_t)br * 256 + col0 + bc * 4);

    for (int s = 0; s < 32; ++s) {
        As[lr][lc * 4 + 0] = av.x;
        As[lr][lc * 4 + 1] = av.y;
        As[lr][lc * 4 + 2] = av.z;
        As[lr][lc * 4 + 3] = av.w;
        *(float4*)&Bs[br][bc * 4] = bv;
        __syncthreads();
        if (s + 1 < 32) {
            int pass = (s + 1) >> 4;
            int k0 = ((s + 1) & 15) << 4;
            int p = pass ? p1 : p0;
            const float* B = pass ? B2 : B1;
            av = (p >= 0) ? *(const float4*)(A + (size_t)p * 256 + k0 + lc * 4)
                          : make_float4(0.f, 0.f, 0.f, 0.f);
            bv = *(const float4*)(B + (size_t)(k0 + br) * 256 + col0 + bc * 4);
        }
        #pragma unroll
        for (int k = 0; k < 16; ++k) {
            float a[4];
            #pragma unroll
            for (int i = 0; i < 4; ++i) a[i] = As[ty * 4 + i][k];
            float4 bb = *(const float4*)&Bs[k][tx * 4];
            const float b[4] = {bb.x, bb.y, bb.z, bb.w};
            #pragma unroll
            for (int i = 0; i < 4; ++i)
                #pragma unroll
                for (int j = 0; j < 4; ++j)
                    acc[i][j] += a[i] * b[j];
        }
        __syncthreads();
    }

    #pragma unroll
    for (int i = 0; i < 4; ++i) {
        int r = row0 + ty * 4 + i;
        if (r < CROWS) {
            #pragma unroll
            for (int j = 0; j < 4; ++j) {
                float v = acc[i][j];
                if (r == 512) v += brow[col0 + tx * 4 + j];
                C[(size_t)r * 256 + col0 + tx * 4 + j] = v;
            }
        }
    }
}

__device__ __forceinline__ void compose_last_dev(
    int bx, const float* __restrict__ A, const float* __restrict__ B1,
    const float* __restrict__ brow, float* __restrict__ Vf, _Float16* __restrict__ BT)
{
    __shared__ float As[64][17];
    __shared__ float Bs[16][64];
    const int tid = threadIdx.x;
    const int tx = tid & 15, ty = tid >> 4;
    const int row0 = bx * 64;
    const int lr = tid >> 2, lc = tid & 3;
    const int br = tid >> 4, bc = tid & 15;

    const int grow = row0 + lr;
    const float* ap = (grow < CROWS) ? (A + (size_t)grow * 256) : nullptr;

    float acc[4][4] = {};

    float4 av = ap ? *(const float4*)(ap + lc * 4) : make_float4(0.f, 0.f, 0.f, 0.f);
    float4 bv = *(const float4*)(B1 + (size_t)br * 64 + bc * 4);

    for (int s = 0; s < 16; ++s) {
        As[lr][lc * 4 + 0] = av.x;
        As[lr][lc * 4 + 1] = av.y;
        As[lr][lc * 4 + 2] = av.z;
        As[lr][lc * 4 + 3] = av.w;
        *(float4*)&Bs[br][bc * 4] = bv;
        __syncthreads();
        if (s + 1 < 16) {
            int k0 = (s + 1) << 4;
            av = ap ? *(const float4*)(ap + k0 + lc * 4) : make_float4(0.f, 0.f, 0.f, 0.f);
            bv = *(const float4*)(B1 + (size_t)(k0 + br) * 64 + bc * 4);
        }
        #pragma unroll
        for (int k = 0; k < 16; ++k) {
            float a[4];
            #pragma unroll
            for (int i = 0; i < 4; ++i) a[i] = As[ty * 4 + i][k];
            float4 bb = *(const float4*)&Bs[k][tx * 4];
            const float b[4] = {bb.x, bb.y, bb.z, bb.w};
            #pragma unroll
            for (int i = 0; i < 4; ++i)
                #pragma unroll
                for (int j = 0; j < 4; ++j)
                    acc[i][j] += a[i] * b[j];
        }
        __syncthreads();
    }

    #pragma unroll
    for (int i = 0; i < 4; ++i) {
        int r = row0 + ty * 4 + i;
        if (r < CROWS) {
            #pragma unroll
            for (int j = 0; j < 4; ++j) {
                int c = tx * 4 + j;
                float v = acc[i][j];
                if (r == 512) v += brow[c];
                Vf[(size_t)r * 64 + c] = v;
                if (r < 512)
                    BT[(size_t)((r >> 7) * 64 + c) * 128 + (r & 127)] = (_Float16)v;
            }
        }
    }
}

// ================= hist (half-range) =================
__device__ __forceinline__ void hist_dev(int bx, int start, int count,
                                         const int* __restrict__ edst,
                                         int* __restrict__ cnt,
                                         unsigned short* __restrict__ rank) {
    int base = start + bx * (256 * HEPT_H) + threadIdx.x;
    int lim = start + count;
    int d[HEPT_H];
    #pragma unroll
    for (int k = 0; k < HEPT_H; ++k) {
        int e = base + k * 256;
        d[k] = (e < lim) ? edst[e] : -1;
    }
    #pragma unroll
    for (int k = 0; k < HEPT_H; ++k) {
        int e = base + k * 256;
        if (d[k] >= 0) rank[e] = (unsigned short)atomicAdd(&cnt[d[k]], 1);
    }
}

// ================= single-dispatch full scan (r7-validated) =================
// Each block bx sums cnt[0 .. bx*256) itself (L2-resident), then local-scans.
__device__ __forceinline__ void scan_full_dev(const int* __restrict__ cnt,
                                              int* __restrict__ offs,
                                              float* __restrict__ dinv, int bx) {
    __shared__ int s[256];
    const int t = threadIdx.x;
    const int limit = bx * 256;
    int p = 0;
    for (int i = t; i < limit; i += 256) p += cnt[i];
    s[t] = p;
    __syncthreads();
    for (int off = 128; off > 0; off >>= 1) {
        if (t < off) s[t] += s[t + off];
        __syncthreads();
    }
    const int base = s[0];
    __syncthreads();
    int i = limit + t;
    int v = (i < NN) ? cnt[i] : 0;
    s[t] = v;
    __syncthreads();
    for (int off = 1; off < 256; off <<= 1) {
        int u = (t >= off) ? s[t - off] : 0;
        __syncthreads();
        s[t] += u;
        __syncthreads();
    }
    if (i < NN) {
        offs[i] = base + s[t] - v;
        dinv[i] = 1.0f / (float)max(v, 1);
    }
    if (i == NN - 1) offs[NN] = base + s[t];
}

// ================= Y GEMM device piece =================
__device__ __forceinline__ void gemm_y_dev(
    int bx, int by,
    const float* __restrict__ X, const _Float16* __restrict__ BT,
    _Float16* __restrict__ Y, _Float16* __restrict__ Tc, int N)
{
    constexpr int LP = 40;
    __shared__ _Float16 As[128 * LP];
    __shared__ _Float16 Bs[128 * LP];

    const int tid = threadIdx.x;
    const int wave = tid >> 6;
    const int lane = tid & 63;
    const int l15 = lane & 15;
    const int quad = lane >> 4;
    const int wrow = wave >> 1;
    const int wcol = wave & 1;
    const int m_base = wrow * 64;
    const int n_base = wcol * 64;

    const int row0 = bx * 128;
    const int col0 = by * 128;

    f32x4 acc[4][4] = {};

    for (int k0 = 0; k0 < 128; k0 += 32) {
        #pragma unroll
        for (int r = 0; r < 2; ++r) {
            int idx = r * 256 + tid;
            int row = idx >> 2, ch = idx & 3;
            int gr = row0 + row; if (gr > N - 1) gr = N - 1;
            const float* ap = X + (size_t)gr * 128 + k0 + ch * 8;
            float4 f0 = *(const float4*)ap;
            float4 f1 = *(const float4*)(ap + 4);
            half8 v = { (_Float16)f0.x, (_Float16)f0.y, (_Float16)f0.z, (_Float16)f0.w,
                        (_Float16)f1.x, (_Float16)f1.y, (_Float16)f1.z, (_Float16)f1.w };
            *(half8*)&As[row * LP + ch * 8] = v;
        }
        #pragma unroll
        for (int r = 0; r < 2; ++r) {
            int idx = r * 256 + tid;
            int row = idx >> 2, ch = idx & 3;
            *(half8*)&Bs[row * LP + ch * 8] =
                *(const half8*)(BT + (size_t)(col0 + row) * 128 + k0 + ch * 8);
        }
        __syncthreads();
        half8 af[4], bf[4];
        #pragma unroll
        for (int i = 0; i < 4; ++i)
            af[i] = *(const half8*)&As[(m_base + i * 16 + l15) * LP + quad * 8];
        #pragma unroll
        for (int j = 0; j < 4; ++j)
            bf[j] = *(const half8*)&Bs[(n_base + j * 16 + l15) * LP + quad * 8];
        #pragma unroll
        for (int i = 0; i < 4; ++i)
            #pragma unroll
            for (int j = 0; j < 4; ++j)
                acc[i][j] = __builtin_amdgcn_mfma_f32_16x16x32_f16(af[i], bf[j], acc[i][j], 0, 0, 0);
        __syncthreads();
    }

    #pragma unroll
    for (int i = 0; i < 4; ++i) {
        #pragma unroll
        for (int j = 0; j < 4; ++j) {
            int col = col0 + n_base + j * 16 + l15;
            #pragma unroll
            for (int r = 0; r < 4; ++r) {
                int row = row0 + m_base + i * 16 + quad * 4 + r;
                if (row < N) {
                    _Float16 v = (_Float16)acc[i][j][r];
                    Y[(size_t)row * 256 + col] = v;
                    if (col >= 192) Tc[(size_t)row * 64 + (col - 192)] = v;
                }
            }
        }
    }
}

// ================= gather node piece =================
template <bool OUT_F32>
__device__ __forceinline__ void gather_node_dev(
    int node, int lane,
    const _Float16* __restrict__ Tin,
    const unsigned short* __restrict__ csr, const int* __restrict__ offs,
    const float* __restrict__ dinv,
    const _Float16* __restrict__ Yadd,
    const float* __restrict__ cvec,
    void* __restrict__ Tout)
{
    int beg = offs[node], end = offs[node + 1];
    float acc[8] = {};
    int e = beg;
    for (; e + 7 < end; e += 8) {
        int s0 = csr[e], s1 = csr[e + 1], s2 = csr[e + 2], s3 = csr[e + 3];
        int s4 = csr[e + 4], s5 = csr[e + 5], s6 = csr[e + 6], s7 = csr[e + 7];
        half8 v0 = *(const half8*)(Tin + (size_t)s0 * 64 + lane * 8);
        half8 v1 = *(const half8*)(Tin + (size_t)s1 * 64 + lane * 8);
        half8 v2 = *(const half8*)(Tin + (size_t)s2 * 64 + lane * 8);
        half8 v3 = *(const half8*)(Tin + (size_t)s3 * 64 + lane * 8);
        half8 v4 = *(const half8*)(Tin + (size_t)s4 * 64 + lane * 8);
        half8 v5 = *(const half8*)(Tin + (size_t)s5 * 64 + lane * 8);
        half8 v6 = *(const half8*)(Tin + (size_t)s6 * 64 + lane * 8);
        half8 v7 = *(const half8*)(Tin + (size_t)s7 * 64 + lane * 8);
        #pragma unroll
        for (int j = 0; j < 8; ++j)
            acc[j] += (((float)v0[j] + (float)v1[j]) + ((float)v2[j] + (float)v3[j]))
                    + (((float)v4[j] + (float)v5[j]) + ((float)v6[j] + (float)v7[j]));
    }
    for (; e + 3 < end; e += 4) {
        int s0 = csr[e], s1 = csr[e + 1], s2 = csr[e + 2], s3 = csr[e + 3];
        half8 v0 = *(const half8*)(Tin + (size_t)s0 * 64 + lane * 8);
        half8 v1 = *(const half8*)(Tin + (size_t)s1 * 64 + lane * 8);
        half8 v2 = *(const half8*)(Tin + (size_t)s2 * 64 + lane * 8);
        half8 v3 = *(const half8*)(Tin + (size_t)s3 * 64 + lane * 8);
        #pragma unroll
        for (int j = 0; j < 8; ++j)
            acc[j] += ((float)v0[j] + (float)v1[j]) + ((float)v2[j] + (float)v3[j]);
    }
    for (; e < end; ++e) {
        half8 v = *(const half8*)(Tin + (size_t)csr[e] * 64 + lane * 8);
        #pragma unroll
        for (int j = 0; j < 8; ++j) acc[j] += (float)v[j];
    }
    float sc = dinv[node];
    half8 y = *(const half8*)(Yadd + (size_t)node * 256 + lane * 8);
    if (OUT_F32) {
        float* o = (float*)Tout + (size_t)node * 64 + lane * 8;
        float4 o0, o1;
        o0.x = acc[0] * sc + (float)y[0] + cvec[lane * 8 + 0];
        o0.y = acc[1] * sc + (float)y[1] + cvec[lane * 8 + 1];
        o0.z = acc[2] * sc + (float)y[2] + cvec[lane * 8 + 2];
        o0.w = acc[3] * sc + (float)y[3] + cvec[lane * 8 + 3];
        o1.x = acc[4] * sc + (float)y[4] + cvec[lane * 8 + 4];
        o1.y = acc[5] * sc + (float)y[5] + cvec[lane * 8 + 5];
        o1.z = acc[6] * sc + (float)y[6] + cvec[lane * 8 + 6];
        o1.w = acc[7] * sc + (float)y[7] + cvec[lane * 8 + 7];
        *(float4*)o = o0;
        *(float4*)(o + 4) = o1;
    } else {
        half8 o;
        #pragma unroll
        for (int j = 0; j < 8; ++j)
            o[j] = (_Float16)(acc[j] * sc + (float)y[j] + cvec[lane * 8 + j]);
        *(half8*)((_Float16*)Tout + (size_t)node * 64 + lane * 8) = o;
    }
}

// ================= packed pipeline kernels =================
// D2: composeF || hist first half
__global__ __launch_bounds__(256) void k_composeF_hist(
    const int* __restrict__ edst, int* __restrict__ cnt, unsigned short* __restrict__ rank,
    const float* __restrict__ W0s, const float* __restrict__ W0n, const float* __restrict__ b0,
    const float* __restrict__ W1s, const float* __restrict__ W1n, const float* __restrict__ b1,
    float* __restrict__ C2)
{
    if (blockIdx.x < CF_BLOCKS) {
        compose_first_dev(blockIdx.x, W0s, W0n, b0, W1s, W1n, b1, C2);
    } else {
        hist_dev(blockIdx.x - CF_BLOCKS, 0, NE_HALF, edst, cnt, rank);
    }
}

// D3: composeM (needs C2) || hist second half
__global__ __launch_bounds__(256) void k_composeM_hist2(
    const int* __restrict__ edst, int* __restrict__ cnt, unsigned short* __restrict__ rank,
    const float* __restrict__ C2,
    const float* __restrict__ W2s, const float* __restrict__ W2n, const float* __restrict__ b2,
    float* __restrict__ C3)
{
    if (blockIdx.x < CF_BLOCKS) compose_mid_dev(blockIdx.x, C2, W2s, W2n, b2, C3);
    else hist_dev(blockIdx.x - CF_BLOCKS, NE_HALF, NE - NE_HALF, edst, cnt, rank);
}

// D4: composeL (needs C3) || single-stage full scan (needs full cnt)
__global__ __launch_bounds__(256) void k_composeL_scan(
    const int* __restrict__ cnt, int* __restrict__ offs, float* __restrict__ dinv,
    const float* __restrict__ C3, const float* __restrict__ Wfc, const float* __restrict__ bfc,
    float* __restrict__ Vf, _Float16* __restrict__ BT)
{
    if (blockIdx.x < CL_BLOCKS) compose_last_dev(blockIdx.x, C3, Wfc, bfc, Vf, BT);
    else scan_full_dev(cnt, offs, dinv, blockIdx.x - CL_BLOCKS);
}

// D5: gemm cols 128..255 (+Tc) || CSR placement (needs offs+rank); place at proven HEPT=4/782
__global__ __launch_bounds__(256) void k_gemmT_place(
    const int* __restrict__ esrc, const int* __restrict__ edst,
    const unsigned short* __restrict__ rank, const int* __restrict__ offs,
    unsigned short* __restrict__ csr,
    const float* __restrict__ X, const _Float16* __restrict__ BT,
    _Float16* __restrict__ Y, _Float16* __restrict__ Tc)
{
    if (blockIdx.x < GA_BLOCKS) {
        gemm_y_dev(blockIdx.x, 1, X, BT, Y, Tc, NN);
    } else {
        int base = (blockIdx.x - GA_BLOCKS) * (256 * HEPT) + threadIdx.x;
        int d[HEPT], s[HEPT], r[HEPT];
        #pragma unroll
        for (int k = 0; k < HEPT; ++k) {
            int e = base + k * 256;
            if (e < NE) { d[k] = edst[e]; s[k] = esrc[e]; r[k] = rank[e]; }
            else d[k] = -1;
        }
        #pragma unroll
        for (int k = 0; k < HEPT; ++k) {
            if (d[k] >= 0) csr[offs[d[k]] + r[k]] = (unsigned short)s[k];
        }
    }
}

// D6: gather1 FIRST (latency-bound phase gets immediate occupancy) || gemm cols 0..127
// (r7's regression suspect was gemm-first ordering starving the gather blocks)
__global__ __launch_bounds__(256) void k_gather1_gemmA(
    const float* __restrict__ X, const _Float16* __restrict__ BT,
    _Float16* __restrict__ Y, _Float16* __restrict__ Tc,
    const unsigned short* __restrict__ csr, const int* __restrict__ offs,
    const float* __restrict__ dinv, const float* __restrict__ Vf,
    _Float16* __restrict__ Ta)
{
    if (blockIdx.x < GG_BLOCKS) {
        int node = blockIdx.x * 32 + (threadIdx.x >> 3);
        int lane = threadIdx.x & 7;
        if (node < NN)
            gather_node_dev<false>(node, lane, Tc, csr, offs, dinv,
                                   Y + 128, Vf + (size_t)514 * 64, (void*)Ta);
    } else {
        gemm_y_dev(blockIdx.x - GG_BLOCKS, 0, X, BT, Y, Tc, NN);
    }
}

// D7/D8: remaining gather passes
template <bool OUT_F32>
__global__ __launch_bounds__(256) void gather64(
    const _Float16* __restrict__ Tin,
    const unsigned short* __restrict__ csr, const int* __restrict__ offs,
    const float* __restrict__ dinv,
    const _Float16* __restrict__ Yadd,
    const float* __restrict__ cvec,
    void* __restrict__ Tout, int N)
{
    int node = blockIdx.x * 32 + (threadIdx.x >> 3);
    int lane = threadIdx.x & 7;
    if (node >= N) return;
    gather_node_dev<OUT_F32>(node, lane, Tin, csr, offs, dinv, Yadd, cvec, Tout);
}

extern "C" void kernel_launch(void* const* d_in, const int* in_sizes, int n_in,
                              void* d_out, int out_size, void* d_ws, size_t ws_size,
                              hipStream_t stream) {
    const float* x    = (const float*)d_in[0];
    const int*   esrc = (const int*)d_in[1];
    const int*   edst = (const int*)d_in[2];
    const float* W0s  = (const float*)d_in[3];
    const float* W0n  = (const float*)d_in[4];
    const float* b0   = (const float*)d_in[5];
    const float* W1s  = (const float*)d_in[6];
    const float* W1n  = (const float*)d_in[7];
    const float* b1   = (const float*)d_in[8];
    const float* W2s  = (const float*)d_in[9];
    const float* W2n  = (const float*)d_in[10];
    const float* b2   = (const float*)d_in[11];
    const float* Wfc  = (const float*)d_in[12];
    const float* bfc  = (const float*)d_in[13];
    float* out = (float*)d_out;

    // ---- workspace layout ----
    _Float16* Y   = (_Float16*)d_ws;                  // N x 256  [Y0|Y1|Y2|Y3]
    _Float16* Ta  = Y + (size_t)NN * 256;             // N x 64
    _Float16* Tb  = Ta + (size_t)NN * 64;             // N x 64
    _Float16* Tc  = Tb + (size_t)NN * 64;             // N x 64 (dense Y3 copy)
    _Float16* BT  = Tc + (size_t)NN * 64;             // 256 x 128
    float* C2     = (float*)(BT + 256 * 128);         // 515 x 256
    float* C3     = C2 + CROWS * 256;                 // 515 x 256
    float* Vf     = C3 + CROWS * 256;                 // 515 x 64
    float* dinv   = Vf + CROWS * 64;                  // N
    int* cnt      = (int*)(dinv + NN);                // N   (memset target)
    int* offs     = cnt + NN;                         // N+1
    int* blockSums = offs + NN + 1;                   // (unused, layout kept)
    unsigned short* rank = (unsigned short*)(blockSums + SCAN_BLOCKS);  // E
    unsigned short* csr  = rank + NE;                 // E

    // D1: zero the histogram counters
    hipMemsetAsync(cnt, 0, (size_t)NN * sizeof(int), stream);

    // D2: weight-compose layer0->1 || degree histogram half A
    k_composeF_hist<<<CF_BLOCKS + HB_H, 256, 0, stream>>>(
        edst, cnt, rank, W0s, W0n, b0, W1s, W1n, b1, C2);

    // D3: weight-compose layer2 || degree histogram half B
    k_composeM_hist2<<<CF_BLOCKS + HB_H, 256, 0, stream>>>(
        edst, cnt, rank, C2, W2s, W2n, b2, C3);

    // D4: final compose (Vf + BT) || single-dispatch full scan (offs, dinv)
    k_composeL_scan<<<CL_BLOCKS + SCAN_BLOCKS, 256, 0, stream>>>(
        cnt, offs, dinv, C3, Wfc, bfc, Vf, BT);

    // D5: gemm Y cols 128..255 (+Tc) || CSR placement
    k_gemmT_place<<<GA_BLOCKS + HB2, 256, 0, stream>>>(
        esrc, edst, rank, offs, csr, x, BT, Y, Tc);

    // D6: gather pass 1 (A*Y3 -> Ta), scheduled FIRST || gemm Y cols 0..127
    k_gather1_gemmA<<<GG_BLOCKS + GA_BLOCKS, 256, 0, stream>>>(
        x, BT, Y, Tc, csr, offs, dinv, Vf, Ta);

    // D7/D8: remaining Horner gather passes
    gather64<false><<<GG_BLOCKS, 256, 0, stream>>>(
        Ta, csr, offs, dinv, Y + 64, Vf + (size_t)513 * 64, (void*)Tb, NN);
    gather64<true><<<GG_BLOCKS, 256, 0, stream>>>(
        Tb, csr, offs, dinv, Y, Vf + (size_t)512 * 64, (void*)out, NN);
}

// Round 10
// 252.862 us; speedup vs baseline: 1.1251x; 1.1251x over previous
//
#include <hip/hip_runtime.h>

#define NN 50000
#define NE 800000
#define F_IN 128
#define HID 256
#define N_CLS 64
#define SCAN_BLOCKS ((NN + 255) / 256)   // 196
#define HEPT 4                           // edges per thread in hist/place
#define HBF ((NE + 256 * HEPT - 1) / (256 * HEPT))   // 782 edge blocks (full range)
#define CF_BLOCKS 36                     // compose 515x256 tiles: 9 row x 4 col
#define PRE_BLOCKS 9                     // Wc precompute: 4+4 tiles + bias
#define CFIN_BLOCKS 9                    // composeFinal 515x64 tiles
#define GA_BLOCKS ((NN + 127) / 128)     // 391 gemm row-blocks per half
#define GG_BLOCKS ((NN + 31) / 32)       // 1563 gather blocks
#define CROWS 515                        // basis: X,AX,A2X,A3X (4*128) + 1,d,Ad

typedef _Float16 half8 __attribute__((ext_vector_type(8)));
typedef float f32x4 __attribute__((ext_vector_type(4)));

// ================= affine-map composition =================
__device__ __forceinline__ const float* virtC1_row(int r, const float* W0s,
                                                   const float* W0n, const float* b0) {
    if (r < 0) return nullptr;
    if (r < 128) return W0s + (size_t)r * 256;
    if (r < 256) return W0n + (size_t)(r - 128) * 256;
    if (r == 512) return b0;
    return nullptr;
}

__device__ __forceinline__ int shift_src(int r) {
    if (r >= 128 && r < 512) return r - 128;
    if (r == 513) return 512;
    if (r == 514) return 513;
    return -1;
}

// layer0->1 compose: C2 = virtC1·W1s + shift(virtC1)·W1n + E·b1  (515x256)
__device__ __forceinline__ void compose_first_dev(
    int bx, const float* __restrict__ W0s, const float* __restrict__ W0n,
    const float* __restrict__ b0,
    const float* __restrict__ B1, const float* __restrict__ B2,
    const float* __restrict__ brow, float* __restrict__ C)
{
    __shared__ float As[64][17];
    __shared__ float Bs[16][64];
    const int tid = threadIdx.x;
    const int tx = tid & 15, ty = tid >> 4;
    const int row0 = (bx % 9) * 64;
    const int col0 = (bx / 9) * 64;
    const int lr = tid >> 2, lc = tid & 3;
    const int br = tid >> 4, bc = tid & 15;

    const int grow = row0 + lr;
    const int srcr0 = (grow < CROWS) ? grow : -1;
    const float* ap0 = virtC1_row(srcr0, W0s, W0n, b0);
    const float* ap1 = virtC1_row(shift_src(grow), W0s, W0n, b0);

    float acc[4][4] = {};

    float4 av = ap0 ? *(const float4*)(ap0 + lc * 4) : make_float4(0.f, 0.f, 0.f, 0.f);
    float4 bv = *(const float4*)(B1 + (size_t)br * 256 + col0 + bc * 4);

    for (int s = 0; s < 32; ++s) {
        As[lr][lc * 4 + 0] = av.x;
        As[lr][lc * 4 + 1] = av.y;
        As[lr][lc * 4 + 2] = av.z;
        As[lr][lc * 4 + 3] = av.w;
        *(float4*)&Bs[br][bc * 4] = bv;
        __syncthreads();
        if (s + 1 < 32) {
            int pass = (s + 1) >> 4;
            int k0 = ((s + 1) & 15) << 4;
            const float* ap = pass ? ap1 : ap0;
            const float* B = pass ? B2 : B1;
            av = ap ? *(const float4*)(ap + k0 + lc * 4) : make_float4(0.f, 0.f, 0.f, 0.f);
            bv = *(const float4*)(B + (size_t)(k0 + br) * 256 + col0 + bc * 4);
        }
        #pragma unroll
        for (int k = 0; k < 16; ++k) {
            float a[4];
            #pragma unroll
            for (int i = 0; i < 4; ++i) a[i] = As[ty * 4 + i][k];
            float4 bb = *(const float4*)&Bs[k][tx * 4];
            const float b[4] = {bb.x, bb.y, bb.z, bb.w};
            #pragma unroll
            for (int i = 0; i < 4; ++i)
                #pragma unroll
                for (int j = 0; j < 4; ++j)
                    acc[i][j] += a[i] * b[j];
        }
        __syncthreads();
    }

    #pragma unroll
    for (int i = 0; i < 4; ++i) {
        int r = row0 + ty * 4 + i;
        if (r < CROWS) {
            #pragma unroll
            for (int j = 0; j < 4; ++j) {
                float v = acc[i][j];
                if (r == 512) v += brow[col0 + tx * 4 + j];
                C[(size_t)r * 256 + col0 + tx * 4 + j] = v;
            }
        }
    }
}

// precompute Wcs = W2s@Wfc, Wcn = W2n@Wfc (256x64 each), bc = b2@Wfc + bfc (64)
// p in 0..3: Wcs row-tile p; 4..7: Wcn row-tile p-4; 8: bias
__device__ __forceinline__ void precompute_dev(
    int p, const float* __restrict__ W2s, const float* __restrict__ W2n,
    const float* __restrict__ b2, const float* __restrict__ Wfc, const float* __restrict__ bfc,
    float* __restrict__ Wcs, float* __restrict__ Wcn, float* __restrict__ bcv)
{
    const int tid = threadIdx.x;
    if (p == 8) {
        if (tid < 64) {
            float s = bfc[tid];
            for (int k = 0; k < 256; ++k) s += b2[k] * Wfc[(size_t)k * 64 + tid];
            bcv[tid] = s;
        }
        return;
    }
    __shared__ float As[64][17];
    __shared__ float Bs[16][64];
    const int tx = tid & 15, ty = tid >> 4;
    const int lr = tid >> 2, lc = tid & 3;
    const int br = tid >> 4, bc = tid & 15;
    const float* M = (p < 4) ? W2s : W2n;
    float* O = (p < 4) ? Wcs : Wcn;
    const int row0 = (p & 3) * 64;

    float acc[4][4] = {};
    float4 av = *(const float4*)(M + (size_t)(row0 + lr) * 256 + lc * 4);
    float4 bv = *(const float4*)(Wfc + (size_t)br * 64 + bc * 4);

    for (int s = 0; s < 16; ++s) {
        As[lr][lc * 4 + 0] = av.x;
        As[lr][lc * 4 + 1] = av.y;
        As[lr][lc * 4 + 2] = av.z;
        As[lr][lc * 4 + 3] = av.w;
        *(float4*)&Bs[br][bc * 4] = bv;
        __syncthreads();
        if (s + 1 < 16) {
            int k0 = (s + 1) << 4;
            av = *(const float4*)(M + (size_t)(row0 + lr) * 256 + k0 + lc * 4);
            bv = *(const float4*)(Wfc + (size_t)(k0 + br) * 64 + bc * 4);
        }
        #pragma unroll
        for (int k = 0; k < 16; ++k) {
            float a[4];
            #pragma unroll
            for (int i = 0; i < 4; ++i) a[i] = As[ty * 4 + i][k];
            float4 bb = *(const float4*)&Bs[k][tx * 4];
            const float b[4] = {bb.x, bb.y, bb.z, bb.w};
            #pragma unroll
            for (int i = 0; i < 4; ++i)
                #pragma unroll
                for (int j = 0; j < 4; ++j)
                    acc[i][j] += a[i] * b[j];
        }
        __syncthreads();
    }
    #pragma unroll
    for (int i = 0; i < 4; ++i)
        #pragma unroll
        for (int j = 0; j < 4; ++j)
            O[(size_t)(row0 + ty * 4 + i) * 64 + tx * 4 + j] = acc[i][j];
}

// composeFinal: Vf = C2·Wcs + shift(C2)·Wcn + E·bc  (515x64), + BT (fp16 transpose)
__device__ __forceinline__ void compose_fin_dev(
    int bx, const float* __restrict__ C2,
    const float* __restrict__ Wcs, const float* __restrict__ Wcn,
    const float* __restrict__ bcv,
    float* __restrict__ Vf, _Float16* __restrict__ BT)
{
    __shared__ float As[64][17];
    __shared__ float Bs[16][64];
    const int tid = threadIdx.x;
    const int tx = tid & 15, ty = tid >> 4;
    const int row0 = bx * 64;
    const int lr = tid >> 2, lc = tid & 3;
    const int br = tid >> 4, bc = tid & 15;

    const int grow = row0 + lr;
    const int p0 = (grow < CROWS) ? grow : -1;
    const int p1 = shift_src(grow);

    float acc[4][4] = {};

    float4 av = (p0 >= 0) ? *(const float4*)(C2 + (size_t)p0 * 256 + lc * 4)
                          : make_float4(0.f, 0.f, 0.f, 0.f);
    float4 bv = *(const float4*)(Wcs + (size_t)br * 64 + bc * 4);

    for (int s = 0; s < 32; ++s) {
        As[lr][lc * 4 + 0] = av.x;
        As[lr][lc * 4 + 1] = av.y;
        As[lr][lc * 4 + 2] = av.z;
        As[lr][lc * 4 + 3] = av.w;
        *(float4*)&Bs[br][bc * 4] = bv;
        __syncthreads();
        if (s + 1 < 32) {
            int pass = (s + 1) >> 4;
            int k0 = ((s + 1) & 15) << 4;
            int p = pass ? p1 : p0;
            const float* B = pass ? Wcn : Wcs;
            av = (p >= 0) ? *(const float4*)(C2 + (size_t)p * 256 + k0 + lc * 4)
                          : make_float4(0.f, 0.f, 0.f, 0.f);
            bv = *(const float4*)(B + (size_t)(k0 + br) * 64 + bc * 4);
        }
        #pragma unroll
        for (int k = 0; k < 16; ++k) {
            float a[4];
            #pragma unroll
            for (int i = 0; i < 4; ++i) a[i] = As[ty * 4 + i][k];
            float4 bb = *(const float4*)&Bs[k][tx * 4];
            const float b[4] = {bb.x, bb.y, bb.z, bb.w};
            #pragma unroll
            for (int i = 0; i < 4; ++i)
                #pragma unroll
                for (int j = 0; j < 4; ++j)
                    acc[i][j] += a[i] * b[j];
        }
        __syncthreads();
    }

    #pragma unroll
    for (int i = 0; i < 4; ++i) {
        int r = row0 + ty * 4 + i;
        if (r < CROWS) {
            #pragma unroll
            for (int j = 0; j < 4; ++j) {
                int c = tx * 4 + j;
                float v = acc[i][j];
                if (r == 512) v += bcv[c];
                Vf[(size_t)r * 64 + c] = v;
                if (r < 512)
                    BT[(size_t)((r >> 7) * 64 + c) * 128 + (r & 127)] = (_Float16)v;
            }
        }
    }
}

// ================= hist (full range, HEPT=4 @ 782 blocks — r3-measured best) =======
__device__ __forceinline__ void hist_dev(int bx, const int* __restrict__ edst,
                                         int* __restrict__ cnt,
                                         unsigned short* __restrict__ rank) {
    int base = bx * (256 * HEPT) + threadIdx.x;
    int d[HEPT];
    #pragma unroll
    for (int k = 0; k < HEPT; ++k) {
        int e = base + k * 256;
        d[k] = (e < NE) ? edst[e] : -1;
    }
    #pragma unroll
    for (int k = 0; k < HEPT; ++k) {
        int e = base + k * 256;
        if (d[k] >= 0) rank[e] = (unsigned short)atomicAdd(&cnt[d[k]], 1);
    }
}

// ================= single-dispatch full scan (r7/r9 refcheck-passed) ============
__device__ __forceinline__ void scan_full_dev(const int* __restrict__ cnt,
                                              int* __restrict__ offs,
                                              float* __restrict__ dinv, int bx) {
    __shared__ int s[256];
    const int t = threadIdx.x;
    const int limit = bx * 256;
    int p = 0;
    for (int i = t; i < limit; i += 256) p += cnt[i];
    s[t] = p;
    __syncthreads();
    for (int off = 128; off > 0; off >>= 1) {
        if (t < off) s[t] += s[t + off];
        __syncthreads();
    }
    const int base = s[0];
    __syncthreads();
    int i = limit + t;
    int v = (i < NN) ? cnt[i] : 0;
    s[t] = v;
    __syncthreads();
    for (int off = 1; off < 256; off <<= 1) {
        int u = (t >= off) ? s[t - off] : 0;
        __syncthreads();
        s[t] += u;
        __syncthreads();
    }
    if (i < NN) {
        offs[i] = base + s[t] - v;
        dinv[i] = 1.0f / (float)max(v, 1);
    }
    if (i == NN - 1) offs[NN] = base + s[t];
}

// ================= Y GEMM device piece =================
__device__ __forceinline__ void gemm_y_dev(
    int bx, int by,
    const float* __restrict__ X, const _Float16* __restrict__ BT,
    _Float16* __restrict__ Y, _Float16* __restrict__ Tc, int N)
{
    constexpr int LP = 40;
    __shared__ _Float16 As[128 * LP];
    __shared__ _Float16 Bs[128 * LP];

    const int tid = threadIdx.x;
    const int wave = tid >> 6;
    const int lane = tid & 63;
    const int l15 = lane & 15;
    const int quad = lane >> 4;
    const int wrow = wave >> 1;
    const int wcol = wave & 1;
    const int m_base = wrow * 64;
    const int n_base = wcol * 64;

    const int row0 = bx * 128;
    const int col0 = by * 128;

    f32x4 acc[4][4] = {};

    for (int k0 = 0; k0 < 128; k0 += 32) {
        #pragma unroll
        for (int r = 0; r < 2; ++r) {
            int idx = r * 256 + tid;
            int row = idx >> 2, ch = idx & 3;
            int gr = row0 + row; if (gr > N - 1) gr = N - 1;
            const float* ap = X + (size_t)gr * 128 + k0 + ch * 8;
            float4 f0 = *(const float4*)ap;
            float4 f1 = *(const float4*)(ap + 4);
            half8 v = { (_Float16)f0.x, (_Float16)f0.y, (_Float16)f0.z, (_Float16)f0.w,
                        (_Float16)f1.x, (_Float16)f1.y, (_Float16)f1.z, (_Float16)f1.w };
            *(half8*)&As[row * LP + ch * 8] = v;
        }
        #pragma unroll
        for (int r = 0; r < 2; ++r) {
            int idx = r * 256 + tid;
            int row = idx >> 2, ch = idx & 3;
            *(half8*)&Bs[row * LP + ch * 8] =
                *(const half8*)(BT + (size_t)(col0 + row) * 128 + k0 + ch * 8);
        }
        __syncthreads();
        half8 af[4], bf[4];
        #pragma unroll
        for (int i = 0; i < 4; ++i)
            af[i] = *(const half8*)&As[(m_base + i * 16 + l15) * LP + quad * 8];
        #pragma unroll
        for (int j = 0; j < 4; ++j)
            bf[j] = *(const half8*)&Bs[(n_base + j * 16 + l15) * LP + quad * 8];
        #pragma unroll
        for (int i = 0; i < 4; ++i)
            #pragma unroll
            for (int j = 0; j < 4; ++j)
                acc[i][j] = __builtin_amdgcn_mfma_f32_16x16x32_f16(af[i], bf[j], acc[i][j], 0, 0, 0);
        __syncthreads();
    }

    #pragma unroll
    for (int i = 0; i < 4; ++i) {
        #pragma unroll
        for (int j = 0; j < 4; ++j) {
            int col = col0 + n_base + j * 16 + l15;
            #pragma unroll
            for (int r = 0; r < 4; ++r) {
                int row = row0 + m_base + i * 16 + quad * 4 + r;
                if (row < N) {
                    _Float16 v = (_Float16)acc[i][j][r];
                    Y[(size_t)row * 256 + col] = v;
                    if (col >= 192) Tc[(size_t)row * 64 + (col - 192)] = v;
                }
            }
        }
    }
}

// ================= gather node piece =================
template <bool OUT_F32>
__device__ __forceinline__ void gather_node_dev(
    int node, int lane,
    const _Float16* __restrict__ Tin,
    const unsigned short* __restrict__ csr, const int* __restrict__ offs,
    const float* __restrict__ dinv,
    const _Float16* __restrict__ Yadd,
    const float* __restrict__ cvec,
    void* __restrict__ Tout)
{
    int beg = offs[node], end = offs[node + 1];
    float acc[8] = {};
    int e = beg;
    for (; e + 7 < end; e += 8) {
        int s0 = csr[e], s1 = csr[e + 1], s2 = csr[e + 2], s3 = csr[e + 3];
        int s4 = csr[e + 4], s5 = csr[e + 5], s6 = csr[e + 6], s7 = csr[e + 7];
        half8 v0 = *(const half8*)(Tin + (size_t)s0 * 64 + lane * 8);
        half8 v1 = *(const half8*)(Tin + (size_t)s1 * 64 + lane * 8);
        half8 v2 = *(const half8*)(Tin + (size_t)s2 * 64 + lane * 8);
        half8 v3 = *(const half8*)(Tin + (size_t)s3 * 64 + lane * 8);
        half8 v4 = *(const half8*)(Tin + (size_t)s4 * 64 + lane * 8);
        half8 v5 = *(const half8*)(Tin + (size_t)s5 * 64 + lane * 8);
        half8 v6 = *(const half8*)(Tin + (size_t)s6 * 64 + lane * 8);
        half8 v7 = *(const half8*)(Tin + (size_t)s7 * 64 + lane * 8);
        #pragma unroll
        for (int j = 0; j < 8; ++j)
            acc[j] += (((float)v0[j] + (float)v1[j]) + ((float)v2[j] + (float)v3[j]))
                    + (((float)v4[j] + (float)v5[j]) + ((float)v6[j] + (float)v7[j]));
    }
    for (; e + 3 < end; e += 4) {
        int s0 = csr[e], s1 = csr[e + 1], s2 = csr[e + 2], s3 = csr[e + 3];
        half8 v0 = *(const half8*)(Tin + (size_t)s0 * 64 + lane * 8);
        half8 v1 = *(const half8*)(Tin + (size_t)s1 * 64 + lane * 8);
        half8 v2 = *(const half8*)(Tin + (size_t)s2 * 64 + lane * 8);
        half8 v3 = *(const half8*)(Tin + (size_t)s3 * 64 + lane * 8);
        #pragma unroll
        for (int j = 0; j < 8; ++j)
            acc[j] += ((float)v0[j] + (float)v1[j]) + ((float)v2[j] + (float)v3[j]);
    }
    for (; e < end; ++e) {
        half8 v = *(const half8*)(Tin + (size_t)csr[e] * 64 + lane * 8);
        #pragma unroll
        for (int j = 0; j < 8; ++j) acc[j] += (float)v[j];
    }
    float sc = dinv[node];
    half8 y = *(const half8*)(Yadd + (size_t)node * 256 + lane * 8);
    if (OUT_F32) {
        float* o = (float*)Tout + (size_t)node * 64 + lane * 8;
        float4 o0, o1;
        o0.x = acc[0] * sc + (float)y[0] + cvec[lane * 8 + 0];
        o0.y = acc[1] * sc + (float)y[1] + cvec[lane * 8 + 1];
        o0.z = acc[2] * sc + (float)y[2] + cvec[lane * 8 + 2];
        o0.w = acc[3] * sc + (float)y[3] + cvec[lane * 8 + 3];
        o1.x = acc[4] * sc + (float)y[4] + cvec[lane * 8 + 4];
        o1.y = acc[5] * sc + (float)y[5] + cvec[lane * 8 + 5];
        o1.z = acc[6] * sc + (float)y[6] + cvec[lane * 8 + 6];
        o1.w = acc[7] * sc + (float)y[7] + cvec[lane * 8 + 7];
        *(float4*)o = o0;
        *(float4*)(o + 4) = o1;
    } else {
        half8 o;
        #pragma unroll
        for (int j = 0; j < 8; ++j)
            o[j] = (_Float16)(acc[j] * sc + (float)y[j] + cvec[lane * 8 + j]);
        *(half8*)((_Float16*)Tout + (size_t)node * 64 + lane * 8) = o;
    }
}

// ================= packed pipeline kernels =================
// D2: composeF || Wc precompute (independent of C2!) || FULL hist
__global__ __launch_bounds__(256) void k_CF_pre_hist(
    const int* __restrict__ edst, int* __restrict__ cnt, unsigned short* __restrict__ rank,
    const float* __restrict__ W0s, const float* __restrict__ W0n, const float* __restrict__ b0,
    const float* __restrict__ W1s, const float* __restrict__ W1n, const float* __restrict__ b1,
    const float* __restrict__ W2s, const float* __restrict__ W2n, const float* __restrict__ b2,
    const float* __restrict__ Wfc, const float* __restrict__ bfc,
    float* __restrict__ C2, float* __restrict__ Wcs, float* __restrict__ Wcn,
    float* __restrict__ bcv)
{
    if (blockIdx.x < CF_BLOCKS) {
        compose_first_dev(blockIdx.x, W0s, W0n, b0, W1s, W1n, b1, C2);
    } else if (blockIdx.x < CF_BLOCKS + PRE_BLOCKS) {
        precompute_dev(blockIdx.x - CF_BLOCKS, W2s, W2n, b2, Wfc, bfc, Wcs, Wcn, bcv);
    } else {
        hist_dev(blockIdx.x - CF_BLOCKS - PRE_BLOCKS, edst, cnt, rank);
    }
}

// D3: composeFinal (needs C2 + Wc) || single-stage full scan (needs full cnt)
__global__ __launch_bounds__(256) void k_CFin_scan(
    const int* __restrict__ cnt, int* __restrict__ offs, float* __restrict__ dinv,
    const float* __restrict__ C2, const float* __restrict__ Wcs,
    const float* __restrict__ Wcn, const float* __restrict__ bcv,
    float* __restrict__ Vf, _Float16* __restrict__ BT)
{
    if (blockIdx.x < CFIN_BLOCKS) compose_fin_dev(blockIdx.x, C2, Wcs, Wcn, bcv, Vf, BT);
    else scan_full_dev(cnt, offs, dinv, blockIdx.x - CFIN_BLOCKS);
}

// D4: BOTH gemm halves (needs BT) || CSR placement (needs offs+rank)
__global__ __launch_bounds__(256) void k_gemm_place(
    const int* __restrict__ esrc, const int* __restrict__ edst,
    const unsigned short* __restrict__ rank, const int* __restrict__ offs,
    unsigned short* __restrict__ csr,
    const float* __restrict__ X, const _Float16* __restrict__ BT,
    _Float16* __restrict__ Y, _Float16* __restrict__ Tc)
{
    if (blockIdx.x < GA_BLOCKS) {
        gemm_y_dev(blockIdx.x, 1, X, BT, Y, Tc, NN);        // cols 128..255 (+Tc)
    } else if (blockIdx.x < 2 * GA_BLOCKS) {
        gemm_y_dev(blockIdx.x - GA_BLOCKS, 0, X, BT, Y, Tc, NN);  // cols 0..127
    } else {
        int base = (blockIdx.x - 2 * GA_BLOCKS) * (256 * HEPT) + threadIdx.x;
        int d[HEPT], s[HEPT], r[HEPT];
        #pragma unroll
        for (int k = 0; k < HEPT; ++k) {
            int e = base + k * 256;
            if (e < NE) { d[k] = edst[e]; s[k] = esrc[e]; r[k] = rank[e]; }
            else d[k] = -1;
        }
        #pragma unroll
        for (int k = 0; k < HEPT; ++k) {
            if (d[k] >= 0) csr[offs[d[k]] + r[k]] = (unsigned short)s[k];
        }
    }
}

// D5-D7: three serial gather passes (kernel-boundary sync; fusion retired r7/r9)
template <bool OUT_F32>
__global__ __launch_bounds__(256) void gather64(
    const _Float16* __restrict__ Tin,
    const unsigned short* __restrict__ csr, const int* __restrict__ offs,
    const float* __restrict__ dinv,
    const _Float16* __restrict__ Yadd,
    const float* __restrict__ cvec,
    void* __restrict__ Tout, int N)
{
    int node = blockIdx.x * 32 + (threadIdx.x >> 3);
    int lane = threadIdx.x & 7;
    if (node >= N) return;
    gather_node_dev<OUT_F32>(node, lane, Tin, csr, offs, dinv, Yadd, cvec, Tout);
}

extern "C" void kernel_launch(void* const* d_in, const int* in_sizes, int n_in,
                              void* d_out, int out_size, void* d_ws, size_t ws_size,
                              hipStream_t stream) {
    const float* x    = (const float*)d_in[0];
    const int*   esrc = (const int*)d_in[1];
    const int*   edst = (const int*)d_in[2];
    const float* W0s  = (const float*)d_in[3];
    const float* W0n  = (const float*)d_in[4];
    const float* b0   = (const float*)d_in[5];
    const float* W1s  = (const float*)d_in[6];
    const float* W1n  = (const float*)d_in[7];
    const float* b1   = (const float*)d_in[8];
    const float* W2s  = (const float*)d_in[9];
    const float* W2n  = (const float*)d_in[10];
    const float* b2   = (const float*)d_in[11];
    const float* Wfc  = (const float*)d_in[12];
    const float* bfc  = (const float*)d_in[13];
    float* out = (float*)d_out;

    // ---- workspace layout ----
    _Float16* Y   = (_Float16*)d_ws;                  // N x 256  [Y0|Y1|Y2|Y3]
    _Float16* Ta  = Y + (size_t)NN * 256;             // N x 64
    _Float16* Tb  = Ta + (size_t)NN * 64;             // N x 64
    _Float16* Tc  = Tb + (size_t)NN * 64;             // N x 64 (dense Y3 copy)
    _Float16* BT  = Tc + (size_t)NN * 64;             // 256 x 128
    float* C2     = (float*)(BT + 256 * 128);         // 515 x 256
    float* Wcs    = C2 + CROWS * 256;                 // 256 x 64  (reuses old C3 slot)
    float* Wcn    = Wcs + 256 * 64;                   // 256 x 64
    float* bcv    = Wcn + 256 * 64;                   // 64
    float* Vf     = bcv + 64;                         // 515 x 64
    float* dinv   = Vf + CROWS * 64;                  // N
    int* cnt      = (int*)(dinv + NN);                // N   (memset target)
    int* offs     = cnt + NN;                         // N+1
    unsigned short* rank = (unsigned short*)(offs + NN + 1);  // E
    unsigned short* csr  = rank + NE;                 // E

    // D1: zero the histogram counters
    hipMemsetAsync(cnt, 0, (size_t)NN * sizeof(int), stream);

    // D2: compose layer0->1 || Wc = (W2s@Wfc, W2n@Wfc, b2@Wfc+bfc) || FULL hist
    k_CF_pre_hist<<<CF_BLOCKS + PRE_BLOCKS + HBF, 256, 0, stream>>>(
        edst, cnt, rank, W0s, W0n, b0, W1s, W1n, b1,
        W2s, W2n, b2, Wfc, bfc, C2, Wcs, Wcn, bcv);

    // D3: composeFinal (C2 -> Vf/BT, skips C3 entirely) || full scan (offs, dinv)
    k_CFin_scan<<<CFIN_BLOCKS + SCAN_BLOCKS, 256, 0, stream>>>(
        cnt, offs, dinv, C2, Wcs, Wcn, bcv, Vf, BT);

    // D4: both gemm halves || CSR placement
    k_gemm_place<<<2 * GA_BLOCKS + HBF, 256, 0, stream>>>(
        esrc, edst, rank, offs, csr, x, BT, Y, Tc);

    // D5-D7: out = Y0 + c1 + A(Y1 + c2 + A(Y2 + c3 + A*Y3))
    gather64<false><<<GG_BLOCKS, 256, 0, stream>>>(
        Tc, csr, offs, dinv, Y + 128, Vf + (size_t)514 * 64, (void*)Ta, NN);
    gather64<false><<<GG_BLOCKS, 256, 0, stream>>>(
        Ta, csr, offs, dinv, Y + 64, Vf + (size_t)513 * 64, (void*)Tb, NN);
    gather64<true><<<GG_BLOCKS, 256, 0, stream>>>(
        Tb, csr, offs, dinv, Y, Vf + (size_t)512 * 64, (void*)out, NN);
}

// Round 11
// 250.024 us; speedup vs baseline: 1.1379x; 1.0114x over previous
//
#include <hip/hip_runtime.h>

#define NN 50000
#define NE 800000
#define F_IN 128
#define HID 256
#define N_CLS 64
#define SCAN_BLOCKS ((NN + 255) / 256)   // 196
#define HEPT 4                           // edges per thread in hist/place
#define HBF ((NE + 256 * HEPT - 1) / (256 * HEPT))   // 782 edge blocks (full range)
#define CF_BLOCKS 36                     // compose 515x256 tiles: 9 row x 4 col
#define PRE_BLOCKS 9                     // Wc precompute: 4+4 tiles + bias
#define CFIN_BLOCKS 9                    // composeFinal 515x64 tiles
#define GA_BLOCKS ((NN + 127) / 128)     // 391 gemm row-blocks per half
#define GG_BLOCKS ((NN + 31) / 32)       // 1563 gather blocks
#define CROWS 515                        // basis: X,AX,A2X,A3X (4*128) + 1,d,Ad

typedef _Float16 half8 __attribute__((ext_vector_type(8)));
typedef float f32x4 __attribute__((ext_vector_type(4)));

// ================= affine-map composition =================
__device__ __forceinline__ const float* virtC1_row(int r, const float* W0s,
                                                   const float* W0n, const float* b0) {
    if (r < 0) return nullptr;
    if (r < 128) return W0s + (size_t)r * 256;
    if (r < 256) return W0n + (size_t)(r - 128) * 256;
    if (r == 512) return b0;
    return nullptr;
}

__device__ __forceinline__ int shift_src(int r) {
    if (r >= 128 && r < 512) return r - 128;
    if (r == 513) return 512;
    if (r == 514) return 513;
    return -1;
}

// layer0->1 compose: C2 = virtC1·W1s + shift(virtC1)·W1n + E·b1  (515x256)
__device__ __forceinline__ void compose_first_dev(
    int bx, const float* __restrict__ W0s, const float* __restrict__ W0n,
    const float* __restrict__ b0,
    const float* __restrict__ B1, const float* __restrict__ B2,
    const float* __restrict__ brow, float* __restrict__ C)
{
    __shared__ float As[64][17];
    __shared__ float Bs[16][64];
    const int tid = threadIdx.x;
    const int tx = tid & 15, ty = tid >> 4;
    const int row0 = (bx % 9) * 64;
    const int col0 = (bx / 9) * 64;
    const int lr = tid >> 2, lc = tid & 3;
    const int br = tid >> 4, bc = tid & 15;

    const int grow = row0 + lr;
    const int srcr0 = (grow < CROWS) ? grow : -1;
    const float* ap0 = virtC1_row(srcr0, W0s, W0n, b0);
    const float* ap1 = virtC1_row(shift_src(grow), W0s, W0n, b0);

    float acc[4][4] = {};

    float4 av = ap0 ? *(const float4*)(ap0 + lc * 4) : make_float4(0.f, 0.f, 0.f, 0.f);
    float4 bv = *(const float4*)(B1 + (size_t)br * 256 + col0 + bc * 4);

    for (int s = 0; s < 32; ++s) {
        As[lr][lc * 4 + 0] = av.x;
        As[lr][lc * 4 + 1] = av.y;
        As[lr][lc * 4 + 2] = av.z;
        As[lr][lc * 4 + 3] = av.w;
        *(float4*)&Bs[br][bc * 4] = bv;
        __syncthreads();
        if (s + 1 < 32) {
            int pass = (s + 1) >> 4;
            int k0 = ((s + 1) & 15) << 4;
            const float* ap = pass ? ap1 : ap0;
            const float* B = pass ? B2 : B1;
            av = ap ? *(const float4*)(ap + k0 + lc * 4) : make_float4(0.f, 0.f, 0.f, 0.f);
            bv = *(const float4*)(B + (size_t)(k0 + br) * 256 + col0 + bc * 4);
        }
        #pragma unroll
        for (int k = 0; k < 16; ++k) {
            float a[4];
            #pragma unroll
            for (int i = 0; i < 4; ++i) a[i] = As[ty * 4 + i][k];
            float4 bb = *(const float4*)&Bs[k][tx * 4];
            const float b[4] = {bb.x, bb.y, bb.z, bb.w};
            #pragma unroll
            for (int i = 0; i < 4; ++i)
                #pragma unroll
                for (int j = 0; j < 4; ++j)
                    acc[i][j] += a[i] * b[j];
        }
        __syncthreads();
    }

    #pragma unroll
    for (int i = 0; i < 4; ++i) {
        int r = row0 + ty * 4 + i;
        if (r < CROWS) {
            #pragma unroll
            for (int j = 0; j < 4; ++j) {
                float v = acc[i][j];
                if (r == 512) v += brow[col0 + tx * 4 + j];
                C[(size_t)r * 256 + col0 + tx * 4 + j] = v;
            }
        }
    }
}

// precompute Wcs = W2s@Wfc, Wcn = W2n@Wfc (256x64 each), bc = b2@Wfc + bfc (64)
__device__ __forceinline__ void precompute_dev(
    int p, const float* __restrict__ W2s, const float* __restrict__ W2n,
    const float* __restrict__ b2, const float* __restrict__ Wfc, const float* __restrict__ bfc,
    float* __restrict__ Wcs, float* __restrict__ Wcn, float* __restrict__ bcv)
{
    const int tid = threadIdx.x;
    if (p == 8) {
        if (tid < 64) {
            float s = bfc[tid];
            for (int k = 0; k < 256; ++k) s += b2[k] * Wfc[(size_t)k * 64 + tid];
            bcv[tid] = s;
        }
        return;
    }
    __shared__ float As[64][17];
    __shared__ float Bs[16][64];
    const int tx = tid & 15, ty = tid >> 4;
    const int lr = tid >> 2, lc = tid & 3;
    const int br = tid >> 4, bc = tid & 15;
    const float* M = (p < 4) ? W2s : W2n;
    float* O = (p < 4) ? Wcs : Wcn;
    const int row0 = (p & 3) * 64;

    float acc[4][4] = {};
    float4 av = *(const float4*)(M + (size_t)(row0 + lr) * 256 + lc * 4);
    float4 bv = *(const float4*)(Wfc + (size_t)br * 64 + bc * 4);

    for (int s = 0; s < 16; ++s) {
        As[lr][lc * 4 + 0] = av.x;
        As[lr][lc * 4 + 1] = av.y;
        As[lr][lc * 4 + 2] = av.z;
        As[lr][lc * 4 + 3] = av.w;
        *(float4*)&Bs[br][bc * 4] = bv;
        __syncthreads();
        if (s + 1 < 16) {
            int k0 = (s + 1) << 4;
            av = *(const float4*)(M + (size_t)(row0 + lr) * 256 + k0 + lc * 4);
            bv = *(const float4*)(Wfc + (size_t)(k0 + br) * 64 + bc * 4);
        }
        #pragma unroll
        for (int k = 0; k < 16; ++k) {
            float a[4];
            #pragma unroll
            for (int i = 0; i < 4; ++i) a[i] = As[ty * 4 + i][k];
            float4 bb = *(const float4*)&Bs[k][tx * 4];
            const float b[4] = {bb.x, bb.y, bb.z, bb.w};
            #pragma unroll
            for (int i = 0; i < 4; ++i)
                #pragma unroll
                for (int j = 0; j < 4; ++j)
                    acc[i][j] += a[i] * b[j];
        }
        __syncthreads();
    }
    #pragma unroll
    for (int i = 0; i < 4; ++i)
        #pragma unroll
        for (int j = 0; j < 4; ++j)
            O[(size_t)(row0 + ty * 4 + i) * 64 + tx * 4 + j] = acc[i][j];
}

// composeFinal: Vf = C2·Wcs + shift(C2)·Wcn + E·bc  (515x64), + BT (fp16 transpose)
__device__ __forceinline__ void compose_fin_dev(
    int bx, const float* __restrict__ C2,
    const float* __restrict__ Wcs, const float* __restrict__ Wcn,
    const float* __restrict__ bcv,
    float* __restrict__ Vf, _Float16* __restrict__ BT)
{
    __shared__ float As[64][17];
    __shared__ float Bs[16][64];
    const int tid = threadIdx.x;
    const int tx = tid & 15, ty = tid >> 4;
    const int row0 = bx * 64;
    const int lr = tid >> 2, lc = tid & 3;
    const int br = tid >> 4, bc = tid & 15;

    const int grow = row0 + lr;
    const int p0 = (grow < CROWS) ? grow : -1;
    const int p1 = shift_src(grow);

    float acc[4][4] = {};

    float4 av = (p0 >= 0) ? *(const float4*)(C2 + (size_t)p0 * 256 + lc * 4)
                          : make_float4(0.f, 0.f, 0.f, 0.f);
    float4 bv = *(const float4*)(Wcs + (size_t)br * 64 + bc * 4);

    for (int s = 0; s < 32; ++s) {
        As[lr][lc * 4 + 0] = av.x;
        As[lr][lc * 4 + 1] = av.y;
        As[lr][lc * 4 + 2] = av.z;
        As[lr][lc * 4 + 3] = av.w;
        *(float4*)&Bs[br][bc * 4] = bv;
        __syncthreads();
        if (s + 1 < 32) {
            int pass = (s + 1) >> 4;
            int k0 = ((s + 1) & 15) << 4;
            int p = pass ? p1 : p0;
            const float* B = pass ? Wcn : Wcs;
            av = (p >= 0) ? *(const float4*)(C2 + (size_t)p * 256 + k0 + lc * 4)
                          : make_float4(0.f, 0.f, 0.f, 0.f);
            bv = *(const float4*)(B + (size_t)(k0 + br) * 64 + bc * 4);
        }
        #pragma unroll
        for (int k = 0; k < 16; ++k) {
            float a[4];
            #pragma unroll
            for (int i = 0; i < 4; ++i) a[i] = As[ty * 4 + i][k];
            float4 bb = *(const float4*)&Bs[k][tx * 4];
            const float b[4] = {bb.x, bb.y, bb.z, bb.w};
            #pragma unroll
            for (int i = 0; i < 4; ++i)
                #pragma unroll
                for (int j = 0; j < 4; ++j)
                    acc[i][j] += a[i] * b[j];
        }
        __syncthreads();
    }

    #pragma unroll
    for (int i = 0; i < 4; ++i) {
        int r = row0 + ty * 4 + i;
        if (r < CROWS) {
            #pragma unroll
            for (int j = 0; j < 4; ++j) {
                int c = tx * 4 + j;
                float v = acc[i][j];
                if (r == 512) v += bcv[c];
                Vf[(size_t)r * 64 + c] = v;
                if (r < 512)
                    BT[(size_t)((r >> 7) * 64 + c) * 128 + (r & 127)] = (_Float16)v;
            }
        }
    }
}

// ================= hist (full range, HEPT=4 @ 782 blocks) =================
__device__ __forceinline__ void hist_dev(int bx, const int* __restrict__ edst,
                                         int* __restrict__ cnt,
                                         unsigned short* __restrict__ rank) {
    int base = bx * (256 * HEPT) + threadIdx.x;
    int d[HEPT];
    #pragma unroll
    for (int k = 0; k < HEPT; ++k) {
        int e = base + k * 256;
        d[k] = (e < NE) ? edst[e] : -1;
    }
    #pragma unroll
    for (int k = 0; k < HEPT; ++k) {
        int e = base + k * 256;
        if (d[k] >= 0) rank[e] = (unsigned short)atomicAdd(&cnt[d[k]], 1);
    }
}

// ================= single-dispatch full scan =================
__device__ __forceinline__ void scan_full_dev(const int* __restrict__ cnt,
                                              int* __restrict__ offs,
                                              float* __restrict__ dinv, int bx) {
    __shared__ int s[256];
    const int t = threadIdx.x;
    const int limit = bx * 256;
    int p = 0;
    for (int i = t; i < limit; i += 256) p += cnt[i];
    s[t] = p;
    __syncthreads();
    for (int off = 128; off > 0; off >>= 1) {
        if (t < off) s[t] += s[t + off];
        __syncthreads();
    }
    const int base = s[0];
    __syncthreads();
    int i = limit + t;
    int v = (i < NN) ? cnt[i] : 0;
    s[t] = v;
    __syncthreads();
    for (int off = 1; off < 256; off <<= 1) {
        int u = (t >= off) ? s[t - off] : 0;
        __syncthreads();
        s[t] += u;
        __syncthreads();
    }
    if (i < NN) {
        offs[i] = base + s[t] - v;
        dinv[i] = 1.0f / (float)max(v, 1);
    }
    if (i == NN - 1) offs[NN] = base + s[t];
}

// ================= Y GEMM: single-shot LDS (K=128 fits whole tile) =================
// r10 defect: 4 k-steps x 2 barriers exposed global latency 4x. Here: all 24
// loads/thread issued back-to-back (max MLP), ONE barrier, 64 straight MFMAs.
// LDS 2x128x136x2B = 68KB -> 2 blocks/CU. Accumulation order (kk=0..3) identical.
__device__ __forceinline__ void gemm_y_dev(
    int bx, int by,
    const float* __restrict__ X, const _Float16* __restrict__ BT,
    _Float16* __restrict__ Y, _Float16* __restrict__ Tc, int N)
{
    constexpr int LP = 136;   // 128 + 8 pad (272B row stride: uniform bank spread)
    __shared__ _Float16 As[128 * LP];
    __shared__ _Float16 Bs[128 * LP];

    const int tid = threadIdx.x;
    const int wave = tid >> 6;
    const int lane = tid & 63;
    const int l15 = lane & 15;
    const int quad = lane >> 4;
    const int wrow = wave >> 1;
    const int wcol = wave & 1;
    const int m_base = wrow * 64;
    const int n_base = wcol * 64;

    const int row0 = bx * 128;
    const int col0 = by * 128;

    // ---- load phase: all global loads issued, no intermediate barriers ----
    #pragma unroll
    for (int k0 = 0; k0 < 128; k0 += 32) {
        #pragma unroll
        for (int r = 0; r < 2; ++r) {
            int idx = r * 256 + tid;
            int row = idx >> 2, ch = idx & 3;
            int gr = row0 + row; if (gr > N - 1) gr = N - 1;
            const float* ap = X + (size_t)gr * 128 + k0 + ch * 8;
            float4 f0 = *(const float4*)ap;
            float4 f1 = *(const float4*)(ap + 4);
            half8 v = { (_Float16)f0.x, (_Float16)f0.y, (_Float16)f0.z, (_Float16)f0.w,
                        (_Float16)f1.x, (_Float16)f1.y, (_Float16)f1.z, (_Float16)f1.w };
            *(half8*)&As[row * LP + k0 + ch * 8] = v;
        }
        #pragma unroll
        for (int r = 0; r < 2; ++r) {
            int idx = r * 256 + tid;
            int row = idx >> 2, ch = idx & 3;
            *(half8*)&Bs[row * LP + k0 + ch * 8] =
                *(const half8*)(BT + (size_t)(col0 + row) * 128 + k0 + ch * 8);
        }
    }
    __syncthreads();

    // ---- compute phase: 64 MFMAs straight-line ----
    f32x4 acc[4][4] = {};
    #pragma unroll
    for (int kk = 0; kk < 4; ++kk) {
        half8 af[4], bf[4];
        #pragma unroll
        for (int i = 0; i < 4; ++i)
            af[i] = *(const half8*)&As[(m_base + i * 16 + l15) * LP + kk * 32 + quad * 8];
        #pragma unroll
        for (int j = 0; j < 4; ++j)
            bf[j] = *(const half8*)&Bs[(n_base + j * 16 + l15) * LP + kk * 32 + quad * 8];
        #pragma unroll
        for (int i = 0; i < 4; ++i)
            #pragma unroll
            for (int j = 0; j < 4; ++j)
                acc[i][j] = __builtin_amdgcn_mfma_f32_16x16x32_f16(af[i], bf[j], acc[i][j], 0, 0, 0);
    }

    #pragma unroll
    for (int i = 0; i < 4; ++i) {
        #pragma unroll
        for (int j = 0; j < 4; ++j) {
            int col = col0 + n_base + j * 16 + l15;
            #pragma unroll
            for (int r = 0; r < 4; ++r) {
                int row = row0 + m_base + i * 16 + quad * 4 + r;
                if (row < N) {
                    _Float16 v = (_Float16)acc[i][j][r];
                    Y[(size_t)row * 256 + col] = v;
                    if (col >= 192) Tc[(size_t)row * 64 + (col - 192)] = v;
                }
            }
        }
    }
}

// ================= gather node piece =================
template <bool OUT_F32>
__device__ __forceinline__ void gather_node_dev(
    int node, int lane,
    const _Float16* __restrict__ Tin,
    const unsigned short* __restrict__ csr, const int* __restrict__ offs,
    const float* __restrict__ dinv,
    const _Float16* __restrict__ Yadd,
    const float* __restrict__ cvec,
    void* __restrict__ Tout)
{
    int beg = offs[node], end = offs[node + 1];
    float acc[8] = {};
    int e = beg;
    for (; e + 7 < end; e += 8) {
        int s0 = csr[e], s1 = csr[e + 1], s2 = csr[e + 2], s3 = csr[e + 3];
        int s4 = csr[e + 4], s5 = csr[e + 5], s6 = csr[e + 6], s7 = csr[e + 7];
        half8 v0 = *(const half8*)(Tin + (size_t)s0 * 64 + lane * 8);
        half8 v1 = *(const half8*)(Tin + (size_t)s1 * 64 + lane * 8);
        half8 v2 = *(const half8*)(Tin + (size_t)s2 * 64 + lane * 8);
        half8 v3 = *(const half8*)(Tin + (size_t)s3 * 64 + lane * 8);
        half8 v4 = *(const half8*)(Tin + (size_t)s4 * 64 + lane * 8);
        half8 v5 = *(const half8*)(Tin + (size_t)s5 * 64 + lane * 8);
        half8 v6 = *(const half8*)(Tin + (size_t)s6 * 64 + lane * 8);
        half8 v7 = *(const half8*)(Tin + (size_t)s7 * 64 + lane * 8);
        #pragma unroll
        for (int j = 0; j < 8; ++j)
            acc[j] += (((float)v0[j] + (float)v1[j]) + ((float)v2[j] + (float)v3[j]))
                    + (((float)v4[j] + (float)v5[j]) + ((float)v6[j] + (float)v7[j]));
    }
    for (; e + 3 < end; e += 4) {
        int s0 = csr[e], s1 = csr[e + 1], s2 = csr[e + 2], s3 = csr[e + 3];
        half8 v0 = *(const half8*)(Tin + (size_t)s0 * 64 + lane * 8);
        half8 v1 = *(const half8*)(Tin + (size_t)s1 * 64 + lane * 8);
        half8 v2 = *(const half8*)(Tin + (size_t)s2 * 64 + lane * 8);
        half8 v3 = *(const half8*)(Tin + (size_t)s3 * 64 + lane * 8);
        #pragma unroll
        for (int j = 0; j < 8; ++j)
            acc[j] += ((float)v0[j] + (float)v1[j]) + ((float)v2[j] + (float)v3[j]);
    }
    for (; e < end; ++e) {
        half8 v = *(const half8*)(Tin + (size_t)csr[e] * 64 + lane * 8);
        #pragma unroll
        for (int j = 0; j < 8; ++j) acc[j] += (float)v[j];
    }
    float sc = dinv[node];
    half8 y = *(const half8*)(Yadd + (size_t)node * 256 + lane * 8);
    if (OUT_F32) {
        float* o = (float*)Tout + (size_t)node * 64 + lane * 8;
        float4 o0, o1;
        o0.x = acc[0] * sc + (float)y[0] + cvec[lane * 8 + 0];
        o0.y = acc[1] * sc + (float)y[1] + cvec[lane * 8 + 1];
        o0.z = acc[2] * sc + (float)y[2] + cvec[lane * 8 + 2];
        o0.w = acc[3] * sc + (float)y[3] + cvec[lane * 8 + 3];
        o1.x = acc[4] * sc + (float)y[4] + cvec[lane * 8 + 4];
        o1.y = acc[5] * sc + (float)y[5] + cvec[lane * 8 + 5];
        o1.z = acc[6] * sc + (float)y[6] + cvec[lane * 8 + 6];
        o1.w = acc[7] * sc + (float)y[7] + cvec[lane * 8 + 7];
        *(float4*)o = o0;
        *(float4*)(o + 4) = o1;
    } else {
        half8 o;
        #pragma unroll
        for (int j = 0; j < 8; ++j)
            o[j] = (_Float16)(acc[j] * sc + (float)y[j] + cvec[lane * 8 + j]);
        *(half8*)((_Float16*)Tout + (size_t)node * 64 + lane * 8) = o;
    }
}

// ================= packed pipeline kernels =================
// D2: composeF || Wc precompute || FULL hist
__global__ __launch_bounds__(256) void k_CF_pre_hist(
    const int* __restrict__ edst, int* __restrict__ cnt, unsigned short* __restrict__ rank,
    const float* __restrict__ W0s, const float* __restrict__ W0n, const float* __restrict__ b0,
    const float* __restrict__ W1s, const float* __restrict__ W1n, const float* __restrict__ b1,
    const float* __restrict__ W2s, const float* __restrict__ W2n, const float* __restrict__ b2,
    const float* __restrict__ Wfc, const float* __restrict__ bfc,
    float* __restrict__ C2, float* __restrict__ Wcs, float* __restrict__ Wcn,
    float* __restrict__ bcv)
{
    if (blockIdx.x < CF_BLOCKS) {
        compose_first_dev(blockIdx.x, W0s, W0n, b0, W1s, W1n, b1, C2);
    } else if (blockIdx.x < CF_BLOCKS + PRE_BLOCKS) {
        precompute_dev(blockIdx.x - CF_BLOCKS, W2s, W2n, b2, Wfc, bfc, Wcs, Wcn, bcv);
    } else {
        hist_dev(blockIdx.x - CF_BLOCKS - PRE_BLOCKS, edst, cnt, rank);
    }
}

// D3: composeFinal (needs C2 + Wc) || single-stage full scan (needs full cnt)
__global__ __launch_bounds__(256) void k_CFin_scan(
    const int* __restrict__ cnt, int* __restrict__ offs, float* __restrict__ dinv,
    const float* __restrict__ C2, const float* __restrict__ Wcs,
    const float* __restrict__ Wcn, const float* __restrict__ bcv,
    float* __restrict__ Vf, _Float16* __restrict__ BT)
{
    if (blockIdx.x < CFIN_BLOCKS) compose_fin_dev(blockIdx.x, C2, Wcs, Wcn, bcv, Vf, BT);
    else scan_full_dev(cnt, offs, dinv, blockIdx.x - CFIN_BLOCKS);
}

// D4: BOTH gemm halves (needs BT) || CSR placement (needs offs+rank)
__global__ __launch_bounds__(256) void k_gemm_place(
    const int* __restrict__ esrc, const int* __restrict__ edst,
    const unsigned short* __restrict__ rank, const int* __restrict__ offs,
    unsigned short* __restrict__ csr,
    const float* __restrict__ X, const _Float16* __restrict__ BT,
    _Float16* __restrict__ Y, _Float16* __restrict__ Tc)
{
    if (blockIdx.x < GA_BLOCKS) {
        gemm_y_dev(blockIdx.x, 1, X, BT, Y, Tc, NN);        // cols 128..255 (+Tc)
    } else if (blockIdx.x < 2 * GA_BLOCKS) {
        gemm_y_dev(blockIdx.x - GA_BLOCKS, 0, X, BT, Y, Tc, NN);  // cols 0..127
    } else {
        int base = (blockIdx.x - 2 * GA_BLOCKS) * (256 * HEPT) + threadIdx.x;
        int d[HEPT], s[HEPT], r[HEPT];
        #pragma unroll
        for (int k = 0; k < HEPT; ++k) {
            int e = base + k * 256;
            if (e < NE) { d[k] = edst[e]; s[k] = esrc[e]; r[k] = rank[e]; }
            else d[k] = -1;
        }
        #pragma unroll
        for (int k = 0; k < HEPT; ++k) {
            if (d[k] >= 0) csr[offs[d[k]] + r[k]] = (unsigned short)s[k];
        }
    }
}

// D5-D7: three serial gather passes (kernel-boundary sync; fusion retired r7/r9)
template <bool OUT_F32>
__global__ __launch_bounds__(256) void gather64(
    const _Float16* __restrict__ Tin,
    const unsigned short* __restrict__ csr, const int* __restrict__ offs,
    const float* __restrict__ dinv,
    const _Float16* __restrict__ Yadd,
    const float* __restrict__ cvec,
    void* __restrict__ Tout, int N)
{
    int node = blockIdx.x * 32 + (threadIdx.x >> 3);
    int lane = threadIdx.x & 7;
    if (node >= N) return;
    gather_node_dev<OUT_F32>(node, lane, Tin, csr, offs, dinv, Yadd, cvec, Tout);
}

extern "C" void kernel_launch(void* const* d_in, const int* in_sizes, int n_in,
                              void* d_out, int out_size, void* d_ws, size_t ws_size,
                              hipStream_t stream) {
    const float* x    = (const float*)d_in[0];
    const int*   esrc = (const int*)d_in[1];
    const int*   edst = (const int*)d_in[2];
    const float* W0s  = (const float*)d_in[3];
    const float* W0n  = (const float*)d_in[4];
    const float* b0   = (const float*)d_in[5];
    const float* W1s  = (const float*)d_in[6];
    const float* W1n  = (const float*)d_in[7];
    const float* b1   = (const float*)d_in[8];
    const float* W2s  = (const float*)d_in[9];
    const float* W2n  = (const float*)d_in[10];
    const float* b2   = (const float*)d_in[11];
    const float* Wfc  = (const float*)d_in[12];
    const float* bfc  = (const float*)d_in[13];
    float* out = (float*)d_out;

    // ---- workspace layout ----
    _Float16* Y   = (_Float16*)d_ws;                  // N x 256  [Y0|Y1|Y2|Y3]
    _Float16* Ta  = Y + (size_t)NN * 256;             // N x 64
    _Float16* Tb  = Ta + (size_t)NN * 64;             // N x 64
    _Float16* Tc  = Tb + (size_t)NN * 64;             // N x 64 (dense Y3 copy)
    _Float16* BT  = Tc + (size_t)NN * 64;             // 256 x 128
    float* C2     = (float*)(BT + 256 * 128);         // 515 x 256
    float* Wcs    = C2 + CROWS * 256;                 // 256 x 64
    float* Wcn    = Wcs + 256 * 64;                   // 256 x 64
    float* bcv    = Wcn + 256 * 64;                   // 64
    float* Vf     = bcv + 64;                         // 515 x 64
    float* dinv   = Vf + CROWS * 64;                  // N
    int* cnt      = (int*)(dinv + NN);                // N   (memset target)
    int* offs     = cnt + NN;                         // N+1
    unsigned short* rank = (unsigned short*)(offs + NN + 1);  // E
    unsigned short* csr  = rank + NE;                 // E

    // D1: zero the histogram counters
    hipMemsetAsync(cnt, 0, (size_t)NN * sizeof(int), stream);

    // D2: compose layer0->1 || Wc = (W2s@Wfc, W2n@Wfc, b2@Wfc+bfc) || FULL hist
    k_CF_pre_hist<<<CF_BLOCKS + PRE_BLOCKS + HBF, 256, 0, stream>>>(
        edst, cnt, rank, W0s, W0n, b0, W1s, W1n, b1,
        W2s, W2n, b2, Wfc, bfc, C2, Wcs, Wcn, bcv);

    // D3: composeFinal (C2 -> Vf/BT) || full scan (offs, dinv)
    k_CFin_scan<<<CFIN_BLOCKS + SCAN_BLOCKS, 256, 0, stream>>>(
        cnt, offs, dinv, C2, Wcs, Wcn, bcv, Vf, BT);

    // D4: both gemm halves (single-shot LDS) || CSR placement
    k_gemm_place<<<2 * GA_BLOCKS + HBF, 256, 0, stream>>>(
        esrc, edst, rank, offs, csr, x, BT, Y, Tc);

    // D5-D7: out = Y0 + c1 + A(Y1 + c2 + A(Y2 + c3 + A*Y3))
    gather64<false><<<GG_BLOCKS, 256, 0, stream>>>(
        Tc, csr, offs, dinv, Y + 128, Vf + (size_t)514 * 64, (void*)Ta, NN);
    gather64<false><<<GG_BLOCKS, 256, 0, stream>>>(
        Ta, csr, offs, dinv, Y + 64, Vf + (size_t)513 * 64, (void*)Tb, NN);
    gather64<true><<<GG_BLOCKS, 256, 0, stream>>>(
        Tb, csr, offs, dinv, Y, Vf + (size_t)512 * 64, (void*)out, NN);
}